// Round 9
// baseline (59.643 us; speedup 1.0000x reference)
//
#include <hip/hip_runtime.h>
#include <math.h>

#define D_DIM 128
#define M_CLUSTERS 64
#define BLOCK 256
#define RBLOCK 1024

typedef __bf16 bf16x8 __attribute__((ext_vector_type(8)));
typedef float f32x4 __attribute__((ext_vector_type(4)));

union B8 { int4 i; bf16x8 b; };
union F4 { float4 v; float f[4]; };

// Inline-asm loads: invisible to compiler's waitcnt tracking; our counted
// vmcnt discipline is exact (vmem completes in issue order, m135).
#define LOADX4(dst, ptr, OFF)                                       \
    asm volatile("global_load_dwordx4 %0, %1, off offset:" #OFF     \
                 : "=v"(dst) : "v"(ptr) : "memory")
#define WAITVM(N_)                                                  \
    do {                                                            \
        asm volatile("s_waitcnt vmcnt(" #N_ ")" ::: "memory");      \
        __builtin_amdgcn_sched_barrier(0);                          \
    } while (0)

__device__ __forceinline__ float zval(float sq) {
    float dd = sqrtf(fmaxf(sq, 0.0f));
    float sg = __fdividef(1.0f, 1.0f + __expf(dd));
    return -__logf(sg + 1e-8f);
}

// Prep (grid=4): muB4 = bf16(mus) [64 clusters][16 slots of 16B]; m2 = ||mu||^2.
__global__ void iso_prep(const float4* __restrict__ mus4, int4* __restrict__ muB4,
                         float* __restrict__ m2) {
    const int f = blockIdx.x * 256 + threadIdx.x;   // 1024 chunks of 8 f32
    float4 v0 = mus4[f * 2 + 0];
    float4 v1 = mus4[f * 2 + 1];
    B8 p;
    p.b[0] = (__bf16)v0.x; p.b[1] = (__bf16)v0.y;
    p.b[2] = (__bf16)v0.z; p.b[3] = (__bf16)v0.w;
    p.b[4] = (__bf16)v1.x; p.b[5] = (__bf16)v1.y;
    p.b[6] = (__bf16)v1.z; p.b[7] = (__bf16)v1.w;
    muB4[f] = p.i;
    if (blockIdx.x == 0 && threadIdx.x < M_CLUSTERS) {
        const float4* mv = mus4 + threadIdx.x * (D_DIM / 4);
        float s = 0.f;
#pragma unroll
        for (int d = 0; d < D_DIM / 4; ++d) {
            float4 v = mv[d];
            s = fmaf(v.x, v.x, s);
            s = fmaf(v.y, v.y, s);
            s = fmaf(v.z, v.z, s);
            s = fmaf(v.w, v.w, s);
        }
        m2[threadIdx.x] = s;
    }
}

// Main: 1 wave = 1 tile of 16 rows, no LDS, swapped-operand MFMA so the
// epilogue is row-per-lane (r loads = 4x dwordx4/lane, x2 local).
__global__ __launch_bounds__(BLOCK, 5) void iso_main(
        const float* __restrict__ X, const float* __restrict__ r,
        const int4* __restrict__ muB4, const float* __restrict__ m2g,
        float* __restrict__ partials, int N, int ntiles) {
    const int tid = threadIdx.x;
    const int lane = tid & 63;
    const int la = lane & 15;
    const int lg = lane >> 4;
    const int w = tid >> 6;
    const int tile = blockIdx.x * 4 + w;

    const int row = tile * 16 + la;                 // this lane's X-row
    const bool ok = (tile < ntiles) && (row < N);
    const size_t crow = ok ? (size_t)row : 0;       // clamp: valid memory

    // ---- Issue order (vmcnt completes in order): X(8) bA(4) bB(4) rv(4) ----
    const char* xb = (const char*)X + crow * 512 + lg * 32;
    float4 xv[8];
    LOADX4(xv[0], xb, 0);   LOADX4(xv[1], xb, 16);
    LOADX4(xv[2], xb, 128); LOADX4(xv[3], xb, 144);
    LOADX4(xv[4], xb, 256); LOADX4(xv[5], xb, 272);
    LOADX4(xv[6], xb, 384); LOADX4(xv[7], xb, 400);

    // mu fragments: lane (la,lg) holds mus[cb*16+la][(kk*4+lg)*8 ..+8].
    const char* bb0 = (const char*)muB4 + la * 256 + lg * 16;
    const char* bb1 = bb0 + 4096;
    const char* bb2 = bb0 + 8192;
    const char* bb3 = bb0 + 12288;
    B8 bA[4], bB[4];
    LOADX4(bA[0].i, bb0, 0);  LOADX4(bA[1].i, bb1, 0);
    LOADX4(bA[2].i, bb2, 0);  LOADX4(bA[3].i, bb3, 0);    // B(kk=0)
    LOADX4(bB[0].i, bb0, 64); LOADX4(bB[1].i, bb1, 64);
    LOADX4(bB[2].i, bb2, 64); LOADX4(bB[3].i, bb3, 64);   // B(kk=1)

    // r: lane needs r[row][cb*16 + lg*4 ..+3] -> 4 contiguous 16B loads.
    const char* rb = (const char*)r + crow * 256 + lg * 16;
    F4 rv[4];
    LOADX4(rv[0].v, rb, 0);   LOADX4(rv[1].v, rb, 64);
    LOADX4(rv[2].v, rb, 128); LOADX4(rv[3].v, rb, 192);

    WAITVM(12);   // drain X(8); bA,bB,rv (12) in flight

    // Convert X -> bf16 fragments; accumulate this lane's quarter of x2.
    B8 xf[4];
    float x2 = 0.f;
#pragma unroll
    for (int kk = 0; kk < 4; ++kk) {
        float4 a = xv[2 * kk], b = xv[2 * kk + 1];
        xf[kk].b[0] = (__bf16)a.x; xf[kk].b[1] = (__bf16)a.y;
        xf[kk].b[2] = (__bf16)a.z; xf[kk].b[3] = (__bf16)a.w;
        xf[kk].b[4] = (__bf16)b.x; xf[kk].b[5] = (__bf16)b.y;
        xf[kk].b[6] = (__bf16)b.z; xf[kk].b[7] = (__bf16)b.w;
        x2 = fmaf(a.x, a.x, x2); x2 = fmaf(a.y, a.y, x2);
        x2 = fmaf(a.z, a.z, x2); x2 = fmaf(a.w, a.w, x2);
        x2 = fmaf(b.x, b.x, x2); x2 = fmaf(b.y, b.y, x2);
        x2 = fmaf(b.z, b.z, x2); x2 = fmaf(b.w, b.w, x2);
    }
    // Quarter-sums live at (la, lg): reduce over lg -> every lane has x2[row la].
    x2 += __shfl_xor(x2, 16, 64);
    x2 += __shfl_xor(x2, 32, 64);

    // ---- MFMA with ping-pong B fragments and exact counted waits ----
    f32x4 acc[4];
#pragma unroll
    for (int cb = 0; cb < 4; ++cb)
#pragma unroll
        for (int q = 0; q < 4; ++q) acc[cb][q] = 0.f;

    WAITVM(8);    // drain bA (B kk0); bB+rv (8) in flight
#pragma unroll
    for (int cb = 0; cb < 4; ++cb)
        acc[cb] = __builtin_amdgcn_mfma_f32_16x16x32_bf16(bA[cb].b, xf[0].b,
                                                          acc[cb], 0, 0, 0);
    LOADX4(bA[0].i, bb0, 128); LOADX4(bA[1].i, bb1, 128);
    LOADX4(bA[2].i, bb2, 128); LOADX4(bA[3].i, bb3, 128);  // B(kk=2)

    WAITVM(8);    // drain bB (kk1); bA'(kk2)+rv in flight
#pragma unroll
    for (int cb = 0; cb < 4; ++cb)
        acc[cb] = __builtin_amdgcn_mfma_f32_16x16x32_bf16(bB[cb].b, xf[1].b,
                                                          acc[cb], 0, 0, 0);
    LOADX4(bB[0].i, bb0, 192); LOADX4(bB[1].i, bb1, 192);
    LOADX4(bB[2].i, bb2, 192); LOADX4(bB[3].i, bb3, 192);  // B(kk=3)

    WAITVM(8);    // drain bA' (kk2); bB'(kk3)+rv in flight
#pragma unroll
    for (int cb = 0; cb < 4; ++cb)
        acc[cb] = __builtin_amdgcn_mfma_f32_16x16x32_bf16(bA[cb].b, xf[2].b,
                                                          acc[cb], 0, 0, 0);

    WAITVM(4);    // drain bB' (kk3); rv in flight
#pragma unroll
    for (int cb = 0; cb < 4; ++cb)
        acc[cb] = __builtin_amdgcn_mfma_f32_16x16x32_bf16(bB[cb].b, xf[3].b,
                                                          acc[cb], 0, 0, 0);

    WAITVM(0);    // rv done

    // m2 (L1-hot, compiler-scheduled; vmcnt empty here so its counts are exact)
    F4 m2r[4];
    const float4* mp = (const float4*)m2g + lg;
#pragma unroll
    for (int cb = 0; cb < 4; ++cb) m2r[cb].v = mp[cb * 4];

    // Epilogue: acc[cb][q] = dot(mu[cb*16+lg*4+q], x[row la]).
    float partial = 0.f;
#pragma unroll
    for (int cb = 0; cb < 4; ++cb)
#pragma unroll
        for (int q = 0; q < 4; ++q) {
            float sq = x2 + m2r[cb].f[q] - 2.0f * acc[cb][q];
            partial = fmaf(rv[cb].f[q], zval(sq), partial);
        }
    if (!ok) partial = 0.f;

    // Wave reduce (lanes cover 16 rows x 64 clusters of this tile).
#pragma unroll
    for (int off = 32; off > 0; off >>= 1)
        partial += __shfl_down(partial, off, 64);
    if (lane == 0 && tile < ntiles) partials[tile] = partial;
}

// Deterministic fixed-order final reduction.
__global__ __launch_bounds__(RBLOCK) void iso_reduce(
        const float* __restrict__ partials, int n,
        float* __restrict__ out, float invN) {
    float s = 0.f;
    for (int i = threadIdx.x; i < n; i += RBLOCK) s += partials[i];
#pragma unroll
    for (int off = 32; off > 0; off >>= 1)
        s += __shfl_down(s, off, 64);
    __shared__ float wsum[RBLOCK / 64];
    const int lane = threadIdx.x & 63;
    const int wid = threadIdx.x >> 6;
    if (lane == 0) wsum[wid] = s;
    __syncthreads();
    if (threadIdx.x == 0) {
        float t = 0.f;
#pragma unroll
        for (int j = 0; j < RBLOCK / 64; ++j) t += wsum[j];
        out[0] = t * invN;
    }
}

extern "C" void kernel_launch(void* const* d_in, const int* in_sizes, int n_in,
                              void* d_out, int out_size, void* d_ws, size_t ws_size,
                              hipStream_t stream) {
    const float* X = (const float*)d_in[0];    // [N,128]
    const float* r = (const float*)d_in[1];    // [N,64]
    const float* mus = (const float*)d_in[2];  // [64,128]
    const int N = in_sizes[0] / D_DIM;

    // ws: muB4 (1024 int4 = 16KB) | m2 (64 f32) | partials (ntiles f32)
    int4* muB4 = (int4*)d_ws;
    float* m2 = (float*)((char*)d_ws + 16384);
    float* partials = m2 + M_CLUSTERS;

    const int ntiles = (N + 15) / 16;
    const int nblocks = (ntiles + 3) / 4;

    hipLaunchKernelGGL(iso_prep, dim3(4), dim3(256), 0, stream,
                       (const float4*)mus, muB4, m2);
    hipLaunchKernelGGL(iso_main, dim3(nblocks), dim3(BLOCK), 0, stream,
                       X, r, muB4, m2, partials, N, ntiles);
    hipLaunchKernelGGL(iso_reduce, dim3(1), dim3(RBLOCK), 0, stream,
                       partials, ntiles, (float*)d_out, 1.0f / (float)N);
}

// Round 11
// 41.318 us; speedup vs baseline: 1.4435x; 1.4435x over previous
//
#include <hip/hip_runtime.h>
#include <math.h>

#define D_DIM 128
#define M_CLUSTERS 64
#define BLOCK 256
#define GRIDB 1024
#define W_TOTAL 4096     // resident waves: 1024 blocks x 4 waves = 4/SIMD
#define RBLOCK 1024

typedef __bf16 bf16x8 __attribute__((ext_vector_type(8)));
typedef float f32x4 __attribute__((ext_vector_type(4)));

union B8 { int4 i; bf16x8 b; };
union F4 { float4 v; float f[4]; };

__device__ __forceinline__ float zval(float sq) {
    float dd = sqrtf(fmaxf(sq, 0.0f));
    float sg = __fdividef(1.0f, 1.0f + __expf(dd));
    return -__logf(sg + 1e-8f);
}

// Async global->LDS, 16B/lane: lds dest = base + lane*16 (HW rule). r6-proven.
__device__ __forceinline__ void gload16(const void* g, void* l) {
    __builtin_amdgcn_global_load_lds(
        (const __attribute__((address_space(1))) unsigned int*)g,
        (__attribute__((address_space(3))) unsigned int*)l, 16, 0, 0);
}

// Prep (grid=4): muB4 = bf16(mus) [64 clusters][16 slots of 16B]; m2 = ||mu||^2.
__global__ void iso_prep(const float4* __restrict__ mus4, int4* __restrict__ muB4,
                         float* __restrict__ m2) {
    const int f = blockIdx.x * 256 + threadIdx.x;   // 1024 chunks of 8 f32
    float4 v0 = mus4[f * 2 + 0];
    float4 v1 = mus4[f * 2 + 1];
    B8 p;
    p.b[0] = (__bf16)v0.x; p.b[1] = (__bf16)v0.y;
    p.b[2] = (__bf16)v0.z; p.b[3] = (__bf16)v0.w;
    p.b[4] = (__bf16)v1.x; p.b[5] = (__bf16)v1.y;
    p.b[6] = (__bf16)v1.z; p.b[7] = (__bf16)v1.w;
    muB4[f] = p.i;
    if (blockIdx.x == 0 && threadIdx.x < M_CLUSTERS) {
        const float4* mv = mus4 + threadIdx.x * (D_DIM / 4);
        float s = 0.f;
#pragma unroll
        for (int d = 0; d < D_DIM / 4; ++d) {
            float4 v = mv[d];
            s = fmaf(v.x, v.x, s);
            s = fmaf(v.y, v.y, s);
            s = fmaf(v.z, v.z, s);
            s = fmaf(v.w, v.w, s);
        }
        m2[threadIdx.x] = s;
    }
}

// Main: 4096 resident waves, 4 unrolled pipeline stages (tiles) per wave.
// B in LDS once per block; X depth-2 reg prefetch; no inline asm anywhere.
__global__ __launch_bounds__(BLOCK, 4) void iso_main(
        const float* __restrict__ X, const float* __restrict__ r,
        const int4* __restrict__ muB4, const float* __restrict__ m2g,
        float* __restrict__ partials, int N) {
    __shared__ __align__(16) char bs[16384];   // B tile, swizzled (r6 layout)

    const int tid = threadIdx.x;
    const int lane = tid & 63;
    const int la = lane & 15;
    const int lg = lane >> 4;
    const int w = tid >> 6;
    const int gid = blockIdx.x * 4 + w;
    const int ntiles = N >> 4;                 // 12500 (16 | N)

    // ---- Prologue: B -> LDS via DMA (verified swizzle), m2 -> regs,
    //      X(tile gid) -> xA. __syncthreads drains everything once. ----
#pragma unroll
    for (int i = 0; i < 4; ++i) {
        int kchunk = w * 4 + i;
        int c = kchunk * 4 + (lane >> 4);
        int slot = (lane & 15) ^ (c & 7);
        gload16(muB4 + c * 16 + slot, bs + kchunk * 1024);
    }
    F4 m2r[4];
    {
        const float4* mp = (const float4*)m2g + lg;
#pragma unroll
        for (int cb = 0; cb < 4; ++cb) m2r[cb].v = mp[cb * 4];
    }
    float4 xA[8], xB[8];
    {
        const char* xb = (const char*)X + (size_t)gid * 8192 +
                         (size_t)la * 512 + lg * 32;
        xA[0] = *(const float4*)(xb + 0);   xA[1] = *(const float4*)(xb + 16);
        xA[2] = *(const float4*)(xb + 128); xA[3] = *(const float4*)(xb + 144);
        xA[4] = *(const float4*)(xb + 256); xA[5] = *(const float4*)(xb + 272);
        xA[6] = *(const float4*)(xb + 384); xA[7] = *(const float4*)(xb + 400);
    }
    __syncthreads();

    float partial = 0.f;

    // One pipeline stage: consume `cur` (tile gid + k*W_TOTAL), prefetch
    // tile k+1 into `nxt`. All array indexing compile-time (rule #20).
    auto run_stage = [&](int k, const float4 (&cur)[8], float4 (&nxt)[8]) {
        const int tk = gid + k * W_TOTAL;
        const bool valid = tk < ntiles;            // wave-uniform
        const size_t ta = valid ? (size_t)tk : (size_t)gid;

        // r loads for this tile (used ~600cy later in the epilogue).
        F4 rv[4];
        const char* rb = (const char*)r + ta * 4096 + (size_t)la * 256 + lg * 16;
        rv[0].v = *(const float4*)(rb + 0);
        rv[1].v = *(const float4*)(rb + 64);
        rv[2].v = *(const float4*)(rb + 128);
        rv[3].v = *(const float4*)(rb + 192);

        // Prefetch X(t+1) into nxt (phantom clamps to gid -> L2-hot, valid).
        int tn = gid + (k + 1) * W_TOTAL;
        if (tn >= ntiles) tn = gid;
        const char* xb = (const char*)X + (size_t)tn * 8192 +
                         (size_t)la * 512 + lg * 32;
        nxt[0] = *(const float4*)(xb + 0);   nxt[1] = *(const float4*)(xb + 16);
        nxt[2] = *(const float4*)(xb + 128); nxt[3] = *(const float4*)(xb + 144);
        nxt[4] = *(const float4*)(xb + 256); nxt[5] = *(const float4*)(xb + 272);
        nxt[6] = *(const float4*)(xb + 384); nxt[7] = *(const float4*)(xb + 400);

        // Pin all the above issues before the compute (loads stay early;
        // compiler's tracked counted-vmcnt inserts the waits at first use).
        __builtin_amdgcn_sched_barrier(0);

        // Convert cur -> bf16 fragments + exact f32 x2.
        B8 xf[4];
        float x2 = 0.f;
#pragma unroll
        for (int kk = 0; kk < 4; ++kk) {
            float4 a = cur[2 * kk], b = cur[2 * kk + 1];
            xf[kk].b[0] = (__bf16)a.x; xf[kk].b[1] = (__bf16)a.y;
            xf[kk].b[2] = (__bf16)a.z; xf[kk].b[3] = (__bf16)a.w;
            xf[kk].b[4] = (__bf16)b.x; xf[kk].b[5] = (__bf16)b.y;
            xf[kk].b[6] = (__bf16)b.z; xf[kk].b[7] = (__bf16)b.w;
            x2 = fmaf(a.x, a.x, x2); x2 = fmaf(a.y, a.y, x2);
            x2 = fmaf(a.z, a.z, x2); x2 = fmaf(a.w, a.w, x2);
            x2 = fmaf(b.x, b.x, x2); x2 = fmaf(b.y, b.y, x2);
            x2 = fmaf(b.z, b.z, x2); x2 = fmaf(b.w, b.w, x2);
        }

        // MFMA: A = mu frags from LDS (swizzle-matched read), B = x frags.
        f32x4 acc[4];
#pragma unroll
        for (int cb = 0; cb < 4; ++cb)
#pragma unroll
            for (int q = 0; q < 4; ++q) acc[cb][q] = 0.f;
#pragma unroll
        for (int kk = 0; kk < 4; ++kk)
#pragma unroll
            for (int cb = 0; cb < 4; ++cb) {
                int c = cb * 16 + la;
                B8 bfr;
                bfr.i = *(const int4*)(bs + c * 256 +
                                       (((kk * 4 + lg) ^ (c & 7)) * 16));
                acc[cb] = __builtin_amdgcn_mfma_f32_16x16x32_bf16(
                    bfr.b, xf[kk].b, acc[cb], 0, 0, 0);
            }

        // x2 quarter-sums at (la,lg) -> reduce over lg; lane keeps row la's x2.
        x2 += __shfl_xor(x2, 16, 64);
        x2 += __shfl_xor(x2, 32, 64);

        // Epilogue: acc[cb][q] = dot(mu[cb*16+lg*4+q], x[row la]) (r9-proven).
        float p = 0.f;
#pragma unroll
        for (int cb = 0; cb < 4; ++cb)
#pragma unroll
            for (int q = 0; q < 4; ++q) {
                float sq = x2 + m2r[cb].f[q] - 2.0f * acc[cb][q];
                p = fmaf(rv[cb].f[q], zval(sq), p);
            }
        if (valid) partial += p;
    };

    run_stage(0, xA, xB);
    run_stage(1, xB, xA);
    run_stage(2, xA, xB);
    run_stage(3, xB, xA);

    // Wave reduce: 64 lanes = 16 rows x 4 cluster-blocks per tile.
#pragma unroll
    for (int off = 32; off > 0; off >>= 1)
        partial += __shfl_down(partial, off, 64);
    if (lane == 0) partials[gid] = partial;
}

// Deterministic fixed-order final reduction over 4096 per-wave partials.
__global__ __launch_bounds__(RBLOCK) void iso_reduce(
        const float* __restrict__ partials, int n,
        float* __restrict__ out, float invN) {
    float s = 0.f;
    for (int i = threadIdx.x; i < n; i += RBLOCK) s += partials[i];
#pragma unroll
    for (int off = 32; off > 0; off >>= 1)
        s += __shfl_down(s, off, 64);
    __shared__ float wsum[RBLOCK / 64];
    const int lane = threadIdx.x & 63;
    const int wid = threadIdx.x >> 6;
    if (lane == 0) wsum[wid] = s;
    __syncthreads();
    if (threadIdx.x == 0) {
        float t = 0.f;
#pragma unroll
        for (int j = 0; j < RBLOCK / 64; ++j) t += wsum[j];
        out[0] = t * invN;
    }
}

extern "C" void kernel_launch(void* const* d_in, const int* in_sizes, int n_in,
                              void* d_out, int out_size, void* d_ws, size_t ws_size,
                              hipStream_t stream) {
    const float* X = (const float*)d_in[0];    // [N,128]
    const float* r = (const float*)d_in[1];    // [N,64]
    const float* mus = (const float*)d_in[2];  // [64,128]
    const int N = in_sizes[0] / D_DIM;

    // ws: muB4 (1024 int4 = 16KB) | m2 (64 f32) | partials (W_TOTAL f32)
    int4* muB4 = (int4*)d_ws;
    float* m2 = (float*)((char*)d_ws + 16384);
    float* partials = m2 + M_CLUSTERS;

    hipLaunchKernelGGL(iso_prep, dim3(4), dim3(256), 0, stream,
                       (const float4*)mus, muB4, m2);
    hipLaunchKernelGGL(iso_main, dim3(GRIDB), dim3(BLOCK), 0, stream,
                       X, r, muB4, m2, partials, N);
    hipLaunchKernelGGL(iso_reduce, dim3(1), dim3(RBLOCK), 0, stream,
                       partials, W_TOTAL, (float*)d_out, 1.0f / (float)N);
}